// Round 8
// baseline (5687.971 us; speedup 1.0000x reference)
//
#include <hip/hip_runtime.h>
#include <hip/hip_bf16.h>
#include <math.h>

typedef __hip_bfloat16 bf16;
typedef short s16x8 __attribute__((ext_vector_type(8)));
typedef float f32x4 __attribute__((ext_vector_type(4)));

#define NN 50000
#define EE 150000
#define EH 75000   // linkpred edge-chunk (2 halves) so t1 fits workspace

static __device__ __forceinline__ float b2f(bf16 x){ return __bfloat162float(x); }
static __device__ __forceinline__ bf16 f2b(float x){ return __float2bfloat16(x); }
static __device__ __forceinline__ short f2s(float x){
  union { bf16 b; short s; } u; u.b = f2b(x); return u.s;
}
static __device__ __forceinline__ float u2f_lo(unsigned u){ union{unsigned i;float f;}c; c.i=u<<16; return c.f; }
static __device__ __forceinline__ float u2f_hi(unsigned u){ union{unsigned i;float f;}c; c.i=u&0xffff0000u; return c.f; }

// ---------------- utility ----------------
__global__ void k_zero(int* __restrict__ p, int n){
  int i = blockIdx.x*blockDim.x + threadIdx.x;
  if(i<n) p[i]=0;
}

// ---------------- CSR build ----------------
__global__ void k_hist(const int* __restrict__ dst, int* __restrict__ deg){
  int i = blockIdx.x*blockDim.x + threadIdx.x;
  if(i<EE) atomicAdd(&deg[dst[i]], 1);
}

__global__ void k_scan(const int* __restrict__ deg, int* __restrict__ rowptr){
  __shared__ int part[1024];
  int tid = threadIdx.x;
  const int n = NN;
  int chunk = (n + 1023)/1024;
  int start = tid*chunk;
  int end = start + chunk; if(end > n) end = n;
  int s = 0;
  for(int i=start;i<end;i++) s += deg[i];
  part[tid] = s; __syncthreads();
  for(int off=1; off<1024; off<<=1){
    int v = (tid>=off)? part[tid-off] : 0;
    __syncthreads();
    part[tid] += v;
    __syncthreads();
  }
  int run = (tid==0)? 0 : part[tid-1];
  for(int i=start;i<end;i++){ rowptr[i]=run; run += deg[i]; }
  if(tid==0) rowptr[n] = part[1023];
}

__global__ void k_scatter(const int* __restrict__ dst, const int* __restrict__ rowptr,
                          int* __restrict__ cursor, int* __restrict__ elist){
  int e = blockIdx.x*blockDim.x + threadIdx.x;
  if(e<EE){ int d=dst[e]; int p=atomicAdd(&cursor[d],1); elist[rowptr[d]+p]=e; }
}

// ------- time encoding -> relpad [E,112] (cols 100..111 zero) -------
__global__ void k_relenc(const int* __restrict__ src, const int* __restrict__ tt,
                         const int* __restrict__ lu, const float* __restrict__ tw,
                         const float* __restrict__ tb, bf16* __restrict__ rel){
  int i = blockIdx.x*blockDim.x + threadIdx.x;
  if(i >= EE*112) return;
  int e = i/112, c = i - e*112;
  float v = 0.f;
  if(c < 100){
    float rt  = (float)(lu[src[e]] - tt[e]);
    float arg = __fadd_rn(__fmul_rn(rt, tw[c]), tb[c]);
    v = cosf(arg);
  }
  rel[i] = f2b(v);
}

// ------- generic weight transpose: WT[n][k] = W[k][colofs+n], bf16, zero-pad --------
__global__ void k_wt2(const float* __restrict__ W, int K, int N, int colofs, int ncols,
                      bf16* __restrict__ WT, int kpad, int nrows){
  int i = blockIdx.x*blockDim.x + threadIdx.x;
  if(i >= nrows*kpad) return;
  int n = i / kpad, k = i - n*kpad;
  float v = (n<ncols && k<K)? W[(size_t)k*N + colofs + n] : 0.f;
  WT[i] = f2b(v);
}

// ------- conv1 stacked weights: 8 heads x [416 rows: q|k|v|s|pad][128] ---------------
__global__ void k_wtc1(const float* __restrict__ qw, const float* __restrict__ kw,
                       const float* __restrict__ vw, const float* __restrict__ sw,
                       bf16* __restrict__ outp){
  int i = blockIdx.x*blockDim.x + threadIdx.x;
  if(i >= 8*416*128) return;
  int h = i/(416*128), r = (i/128)%416, k = i&127;
  float v = 0.f;
  if(r < 400 && k < 100){
    int s = r/100, n = r - s*100;
    const float* W = s==0? qw : s==1? kw : s==2? vw : sw;
    v = W[(size_t)k*800 + h*100 + n];
  }
  outp[i] = f2b(v);
}

// ------- edge weights [112][256]: k<100 -> rel rows, 128..227 -> msg rows (shifted) ---
__global__ void k_wte(const float* __restrict__ ew, int N, int colofs,
                      bf16* __restrict__ outp){
  int i = blockIdx.x*blockDim.x + threadIdx.x;
  if(i >= 112*256) return;
  int r = i>>8, k = i&255;
  float v = 0.f;
  if(r < 100){
    if(k < 100) v = ew[(size_t)k*N + colofs + r];
    else if(k >= 128 && k < 228) v = ew[(size_t)(k-28)*N + colofs + r];
  }
  outp[i] = f2b(v);
}

// ------- stacked bias ----------------
__global__ void k_bstack(const float* __restrict__ b0, const float* __restrict__ b1,
                         const float* __restrict__ b2, const float* __restrict__ b3,
                         int W, int H, float* __restrict__ outp){
  int i = blockIdx.x*blockDim.x + threadIdx.x;
  if(i >= H*4*W) return;
  int h = i/(4*W), r = i - h*4*W, s = r/W, c = r - s*W;
  const float* b = s==0? b0 : s==1? b1 : s==2? b2 : b3;
  outp[i] = b[h*W + c];
}

// ---------------- MFMA GEMM with 16B/lane staging ----------------
// A row i (optional gather): k<ksplit -> A1 bf16 (lda1 rows 16B-aligned), else A2 fp32.
// WT [nstrips*NT*16][kpad] bf16 zero-padded; blockIdx.y = n-strip. act: 0/1 relu/2 tanh.
#define AK 128
#define AST 136   // 136 mod 64 == 8 -> ds_read_b128 2-way bank alias (free)

template<int NT>
__global__ __launch_bounds__(256) void mm_mfma(
    const bf16* __restrict__ A1, int lda1, int ksplit, int k1valid,
    const float* __restrict__ A2, int lda2, int k2valid,
    const int* __restrict__ gather,
    const bf16* __restrict__ WT, int kpad,
    const float* __restrict__ bias,
    bf16* __restrict__ C, int ldc,
    int M, int nvalid, int act)
{
  __shared__ __align__(16) bf16 As[64*AST];
  int tid = threadIdx.x;
  int wave = tid>>6, lane = tid&63;
  int quad = lane>>4, lo = lane&15;
  int m0 = blockIdx.x*64;
  int nstrip = blockIdx.y;
  WT   += (size_t)nstrip*NT*16*kpad;
  if(bias) bias += nstrip*NT*16;
  C    += nstrip*NT*16;
  int nval = nvalid - nstrip*NT*16;
  f32x4 acc[NT];
#pragma unroll
  for(int t=0;t<NT;t++) acc[t]=(f32x4){0.f,0.f,0.f,0.f};
  int nchunks = kpad>>7;
  for(int kc=0; kc<nchunks; kc++){
    int kbase = kc<<7;
#pragma unroll
    for(int it=0; it<4; it++){
      int g = tid + it*256;
      int r = g>>4, k8 = g&15;
      int k = kbase + (k8<<3);
      int row = m0 + r;
      s16x8 val = (s16x8){0,0,0,0,0,0,0,0};
      if(row < M){
        int ar = gather ? gather[row] : row;
        if(k < ksplit){
          if(k + 8 <= k1valid)
            val = *(const s16x8*)(A1 + (size_t)ar*lda1 + k);
        } else {
          int kk = k - ksplit;
          const float* ap = A2 + (size_t)ar*lda2 + kk;
          float4 f0 = {0.f,0.f,0.f,0.f}, f1 = {0.f,0.f,0.f,0.f};
          if(kk + 4 <= k2valid) f0 = *(const float4*)ap;
          if(kk + 8 <= k2valid) f1 = *(const float4*)(ap+4);
          val[0]=f2s(f0.x); val[1]=f2s(f0.y); val[2]=f2s(f0.z); val[3]=f2s(f0.w);
          val[4]=f2s(f1.x); val[5]=f2s(f1.y); val[6]=f2s(f1.z); val[7]=f2s(f1.w);
        }
      }
      *(s16x8*)(As + r*AST + (k8<<3)) = val;
    }
    __syncthreads();
    const bf16* arow = As + (wave*16 + lo)*AST;
#pragma unroll
    for(int ks=0; ks<4; ks++){
      s16x8 af = *(const s16x8*)(arow + ks*32 + quad*8);
#pragma unroll
      for(int nt=0; nt<NT; nt++){
        const bf16* bp = WT + (size_t)(nt*16+lo)*kpad + kbase + ks*32 + quad*8;
        s16x8 bfr = *(const s16x8*)bp;
        acc[nt] = __builtin_amdgcn_mfma_f32_16x16x32_bf16(af, bfr, acc[nt], 0,0,0);
      }
    }
    __syncthreads();
  }
  int mrow0 = m0 + wave*16 + quad*4;
#pragma unroll
  for(int nt=0; nt<NT; nt++){
    int col = nt*16 + lo;
    if(col >= nval) continue;
    float bv = bias? bias[col] : 0.f;
#pragma unroll
    for(int r=0;r<4;r++){
      int row = mrow0 + r;
      if(row >= M) continue;
      float v = acc[nt][r] + bv;
      if(act==1) v = fmaxf(v,0.f);
      else if(act==2) v = tanhf(v);
      C[(size_t)row*ldc+col] = f2b(v);
    }
  }
}

// ------ fused attention: one wave per node; online softmax; skip-add + relu ------
// zpad!=0: also zero output cols 100..111 (for 112-padded h2)
__global__ __launch_bounds__(256) void k_attn(
    const int* __restrict__ rowptr, const int* __restrict__ elist,
    const int* __restrict__ srcv,
    const bf16* __restrict__ qkvs, const bf16* __restrict__ eh,
    bf16* __restrict__ hout, int ldh, int colofs, int zpad)
{
  int wave = threadIdx.x>>6, lane = threadIdx.x&63;
  int node = blockIdx.x*4 + wave;
  if(node >= NN) return;
  bool act = (lane < 50);
  float q0=0.f, q1=0.f;
  const unsigned* qrow = (const unsigned*)(qkvs + (size_t)node*400);
  if(act){ unsigned u = qrow[lane]; q0=u2f_lo(u); q1=u2f_hi(u); }
  int s0 = rowptr[node], s1 = rowptr[node+1];
  float m = -3.4e38f, d = 0.f, a0 = 0.f, a1 = 0.f;
  for(int j=s0; j<s1; j++){
    int e = elist[j];
    int sn = srcv[e];
    float p = 0.f, e0=0.f, e1=0.f;
    if(act){
      unsigned uk = ((const unsigned*)(qkvs + (size_t)sn*400 + 100))[lane];
      unsigned ue = ((const unsigned*)(eh   + (size_t)e*100))[lane];
      e0=u2f_lo(ue); e1=u2f_hi(ue);
      p = q0*(u2f_lo(uk)+e0) + q1*(u2f_hi(uk)+e1);
    }
    for(int off=32; off; off>>=1) p += __shfl_xor(p, off);
    float alpha = p * 0.1f;
    float mn = fmaxf(m, alpha);
    float sc = expf(m - mn);
    float wv = expf(alpha - mn);
    d = d*sc + wv;
    if(act){
      unsigned uv = ((const unsigned*)(qkvs + (size_t)sn*400 + 200))[lane];
      a0 = a0*sc + wv*(u2f_lo(uv)+e0);
      a1 = a1*sc + wv*(u2f_hi(uv)+e1);
    }
    m = mn;
  }
  if(act){
    float inv = 1.f/(d + 1e-16f);
    unsigned us = ((const unsigned*)(qkvs + (size_t)node*400 + 300))[lane];
    float h0 = fmaxf(u2f_lo(us) + a0*inv, 0.f);
    float h1 = fmaxf(u2f_hi(us) + a1*inv, 0.f);
    bf16* op = hout + (size_t)node*ldh + colofs + lane*2;
    op[0] = f2b(h0); op[1] = f2b(h1);
  } else if(zpad && lane < 56){
    bf16* op = hout + (size_t)node*ldh + colofs + lane*2;
    op[0] = f2b(0.f); op[1] = f2b(0.f);
  }
}

// ------ linkpred final layer: out[e] = t3[e] @ w4 + b4 (K=50, N=2, fp32) ------
__global__ void k_lpout(const bf16* __restrict__ t3, const float* __restrict__ w4,
                        const float* __restrict__ b4, float* __restrict__ out,
                        int base, int n){
  int i = blockIdx.x*blockDim.x + threadIdx.x;
  if(i >= n*2) return;
  int g = i>>1, j = i&1;
  const bf16* tp = t3 + (size_t)g*50;
  float s = 0.f;
  for(int k=0;k<50;k++) s += b2f(tp[k])*w4[k*2+j];
  out[(size_t)(base+g)*2 + j] = s + b4[j];
}

extern "C" void kernel_launch(void* const* d_in, const int* in_sizes, int n_in,
                              void* d_out, int out_size, void* d_ws, size_t ws_size,
                              hipStream_t stream){
  const float* x       = (const float*)d_in[0];
  const float* msg     = (const float*)d_in[1];
  const float* time_w  = (const float*)d_in[2];
  const float* time_b  = (const float*)d_in[3];
  const float* c1_qw=(const float*)d_in[4];  const float* c1_qb=(const float*)d_in[5];
  const float* c1_kw=(const float*)d_in[6];  const float* c1_kb=(const float*)d_in[7];
  const float* c1_vw=(const float*)d_in[8];  const float* c1_vb=(const float*)d_in[9];
  const float* c1_ew=(const float*)d_in[10];
  const float* c1_sw=(const float*)d_in[11]; const float* c1_sb=(const float*)d_in[12];
  const float* c2_qw=(const float*)d_in[13]; const float* c2_qb=(const float*)d_in[14];
  const float* c2_kw=(const float*)d_in[15]; const float* c2_kb=(const float*)d_in[16];
  const float* c2_vw=(const float*)d_in[17]; const float* c2_vb=(const float*)d_in[18];
  const float* c2_ew=(const float*)d_in[19];
  const float* c2_sw=(const float*)d_in[20]; const float* c2_sb=(const float*)d_in[21];
  const float* lp_src_w=(const float*)d_in[22]; const float* lp_src_b=(const float*)d_in[23];
  const float* lp_dst_w=(const float*)d_in[24]; const float* lp_dst_b=(const float*)d_in[25];
  const float* lp1_w=(const float*)d_in[26]; const float* lp1_b=(const float*)d_in[27];
  const float* lp2_w=(const float*)d_in[28]; const float* lp2_b=(const float*)d_in[29];
  const float* lp3_w=(const float*)d_in[30]; const float* lp3_b=(const float*)d_in[31];
  const float* lp4_w=(const float*)d_in[32]; const float* lp4_b=(const float*)d_in[33];
  const int* last_update=(const int*)d_in[34];
  const int* tt =(const int*)d_in[35];
  const int* edge_index=(const int*)d_in[36];
  const int* src = edge_index;
  const int* dst = edge_index + EE;
  float* out = (float*)d_out;

  // ---- workspace: peak 199.5 MB (< proved-safe 201.8 MB) ----
  char* ws = (char*)d_ws;
  bf16*  h1    = (bf16*) (ws + 0);             // N*800 bf16
  bf16*  relpad= (bf16*) (ws + 80000000);      // E*112 bf16
  bf16*  eh    = (bf16*) (ws + 113600000);     // E*100 bf16
  bf16*  qkvs  = (bf16*) (ws + 143600000);     // N*400 bf16
  bf16*  h2p   = (bf16*) (ws + 183600000);     // N*112 bf16 (16B-aligned rows)
  int*   rowptr= (int*)  (ws + 194800000);     // N+1
  int*   elist = (int*)  (ws + 195000064);     // E
  int*   deg   = (int*)  (ws + 195600064);     // N
  int*   cursor= (int*)  (ws + 195800064);     // N
  bf16* c1all  = (bf16*)(ws + 196000064);  // 8 x [416][128]
  bf16* c1eall = (bf16*)(ws + 196852032);  // 8 x [112][256]
  bf16* c2all  = (bf16*)(ws + 197310784);  // [416][896]
  bf16* c2e    = (bf16*)(ws + 198056256);  // [112][256]
  bf16* lpswt  = (bf16*)(ws + 198113600);  // [208][128]
  bf16* lpdwt  = (bf16*)(ws + 198166848);  // [208][128]
  bf16* lp1t   = (bf16*)(ws + 198220096);  // [800][512]
  bf16* lp2t   = (bf16*)(ws + 199039296);  // [208][896]
  bf16* lp3t   = (bf16*)(ws + 199412032);  // [64][256]
  float* c1ball= (float*)(ws + 199444800); // [8][400]
  float* c2ball= (float*)(ws + 199457600); // [400] -> ends 199,459,200
  // linkpred-phase overlays (conv buffers 0..183.6MB dead):
  bf16* lhh = (bf16*)(ws + 0);             // EH*400 bf16 = 60 MB
  bf16* lt1 = (bf16*)(ws + 60000000);      // EH*800 bf16 = 120 MB -> 180 MB
  bf16* lt2 = (bf16*)(ws + 0);             // EH*200 bf16 = 30 MB (hh dead)
  bf16* lt3 = (bf16*)(ws + 30000000);      // EH*50  bf16 = 7.5 MB

  // ---- weight conversion ----
  k_wtc1<<<(8*416*128+255)/256,256,0,stream>>>(c1_qw,c1_kw,c1_vw,c1_sw,c1all);
  for(int h=0; h<8; h++)
    k_wte<<<(112*256+255)/256,256,0,stream>>>(c1_ew, 800, h*100, c1eall + (size_t)h*112*256);
  k_wte<<<(112*256+255)/256,256,0,stream>>>(c2_ew, 100, 0, c2e);
  k_wt2<<<(100*896+255)/256,256,0,stream>>>(c2_qw,800,100,0,100,c2all,           896,100);
  k_wt2<<<(100*896+255)/256,256,0,stream>>>(c2_kw,800,100,0,100,c2all+100*896,   896,100);
  k_wt2<<<(100*896+255)/256,256,0,stream>>>(c2_vw,800,100,0,100,c2all+200*896,   896,100);
  k_wt2<<<(116*896+255)/256,256,0,stream>>>(c2_sw,800,100,0,100,c2all+300*896,   896,116);
  k_wt2<<<(208*128+255)/256,256,0,stream>>>(lp_src_w,100,200,0,200,lpswt,128,208);
  k_wt2<<<(208*128+255)/256,256,0,stream>>>(lp_dst_w,100,200,0,200,lpdwt,128,208);
  k_wt2<<<(800*512+255)/256,256,0,stream>>>(lp1_w,400,800,0,800,lp1t,512,800);
  k_wt2<<<(208*896+255)/256,256,0,stream>>>(lp2_w,800,200,0,200,lp2t,896,208);
  k_wt2<<<(64*256+255)/256,256,0,stream>>>(lp3_w,200,50,0,50,lp3t,256,64);
  k_bstack<<<(3200+255)/256,256,0,stream>>>(c1_qb,c1_kb,c1_vb,c1_sb,100,8,c1ball);
  k_bstack<<<(400+255)/256,256,0,stream>>>(c2_qb,c2_kb,c2_vb,c2_sb,100,1,c2ball);

  // ---- CSR build ----
  k_zero   <<<(NN+255)/256, 256, 0, stream>>>(deg, NN);
  k_zero   <<<(NN+255)/256, 256, 0, stream>>>(cursor, NN);
  k_hist   <<<(EE+255)/256, 256, 0, stream>>>(dst, deg);
  k_scan   <<<1, 1024, 0, stream>>>(deg, rowptr);
  k_scatter<<<(EE+255)/256, 256, 0, stream>>>(dst, rowptr, cursor, elist);

  // ---- time encoding ----
  k_relenc<<<(EE*112+255)/256, 256, 0, stream>>>(src, tt, last_update, time_w, time_b, relpad);

  int gN = (NN+63)/64, gE = (EE+63)/64, gA = (NN+3)/4, gL = (EH+63)/64;

  // ---- conv1: per head = stacked GEMM (2 n-strips) + edge GEMM + fused attention ----
  for(int h=0; h<8; h++){
    mm_mfma<13><<<dim3(gN,2),256,0,stream>>>(nullptr,0,0,0, x,100,100, nullptr,
        c1all + (size_t)h*416*128, 128, c1ball + h*400, qkvs,400, NN,400,0);
    mm_mfma<7><<<gE,256,0,stream>>>(relpad,112,128,112, msg,100,100, nullptr,
        c1eall + (size_t)h*112*256, 256, nullptr, eh,100, EE,100,0);
    k_attn<<<gA,256,0,stream>>>(rowptr, elist, src, qkvs, eh, h1, 800, h*100, 0);
  }

  // ---- conv2 (h2 written 112-padded, pad cols zeroed) ----
  mm_mfma<13><<<dim3(gN,2),256,0,stream>>>(h1,800,896,800, nullptr,0,0, nullptr,
      c2all,896, c2ball, qkvs,400, NN,400,0);
  mm_mfma<7><<<gE,256,0,stream>>>(relpad,112,128,112, msg,100,100, nullptr,
      c2e,256, nullptr, eh,100, EE,100,0);
  k_attn<<<gA,256,0,stream>>>(rowptr, elist, src, qkvs, eh, h2p, 112, 0, 1);

  // ---- link predictor: batched MFMA chain (fast staging), 2 edge-halves ----
  for(int half=0; half<2; half++){
    const int* esrc = src + half*EH;
    const int* edst = dst + half*EH;
    // hh[:,0:200] = h2[src]@Wsrc+b ; hh[:,200:400] = h2[dst]@Wdst+b  (gathered A, K=100)
    mm_mfma<13><<<gL,256,0,stream>>>(h2p,112,128,112, nullptr,0,0, esrc,
        lpswt,128, lp_src_b, lhh,400, EH,200,0);
    mm_mfma<13><<<gL,256,0,stream>>>(h2p,112,128,112, nullptr,0,0, edst,
        lpdwt,128, lp_dst_b, lhh+200,400, EH,200,0);
    // t1 = tanh(hh@W1+b1): K=400(512), N=800 via 2 n-strips of 400
    mm_mfma<25><<<dim3(gL,2),256,0,stream>>>(lhh,400,512,400, nullptr,0,0, nullptr,
        lp1t,512, lp1_b, lt1,800, EH,800,2);
    // t2 = tanh(t1@W2+b2): K=800(896), N=200
    mm_mfma<13><<<gL,256,0,stream>>>(lt1,800,896,800, nullptr,0,0, nullptr,
        lp2t,896, lp2_b, lt2,200, EH,200,2);
    // t3 = tanh(t2@W3+b3): K=200(256), N=50
    mm_mfma<4><<<gL,256,0,stream>>>(lt2,200,256,200, nullptr,0,0, nullptr,
        lp3t,256, lp3_b, lt3,50, EH,50,2);
    // out = t3@W4+b4
    k_lpout<<<(EH*2+255)/256,256,0,stream>>>(lt3, lp4_w, lp4_b, out, half*EH, EH);
  }

  (void)in_sizes; (void)n_in; (void)out_size; (void)ws_size;
}

// Round 9
// 3823.007 us; speedup vs baseline: 1.4878x; 1.4878x over previous
//
#include <hip/hip_runtime.h>
#include <hip/hip_bf16.h>
#include <math.h>

typedef __hip_bfloat16 bf16;
typedef short s16x8 __attribute__((ext_vector_type(8)));
typedef float f32x4 __attribute__((ext_vector_type(4)));

#define NN 50000
#define EE 150000
#define EH 75000   // linkpred edge-chunk (2 halves) so t1 fits workspace

static __device__ __forceinline__ float b2f(bf16 x){ return __bfloat162float(x); }
static __device__ __forceinline__ bf16 f2b(float x){ return __float2bfloat16(x); }
static __device__ __forceinline__ short f2s(float x){
  union { bf16 b; short s; } u; u.b = f2b(x); return u.s;
}
static __device__ __forceinline__ float u2f_lo(unsigned u){ union{unsigned i;float f;}c; c.i=u<<16; return c.f; }
static __device__ __forceinline__ float u2f_hi(unsigned u){ union{unsigned i;float f;}c; c.i=u&0xffff0000u; return c.f; }

// ---------------- utility ----------------
__global__ void k_zero(int* __restrict__ p, int n){
  int i = blockIdx.x*blockDim.x + threadIdx.x;
  if(i<n) p[i]=0;
}

// ---------------- CSR build ----------------
__global__ void k_hist(const int* __restrict__ dst, int* __restrict__ deg){
  int i = blockIdx.x*blockDim.x + threadIdx.x;
  if(i<EE) atomicAdd(&deg[dst[i]], 1);
}

__global__ void k_scan(const int* __restrict__ deg, int* __restrict__ rowptr){
  __shared__ int part[1024];
  int tid = threadIdx.x;
  const int n = NN;
  int chunk = (n + 1023)/1024;
  int start = tid*chunk;
  int end = start + chunk; if(end > n) end = n;
  int s = 0;
  for(int i=start;i<end;i++) s += deg[i];
  part[tid] = s; __syncthreads();
  for(int off=1; off<1024; off<<=1){
    int v = (tid>=off)? part[tid-off] : 0;
    __syncthreads();
    part[tid] += v;
    __syncthreads();
  }
  int run = (tid==0)? 0 : part[tid-1];
  for(int i=start;i<end;i++){ rowptr[i]=run; run += deg[i]; }
  if(tid==0) rowptr[n] = part[1023];
}

__global__ void k_scatter(const int* __restrict__ dst, const int* __restrict__ rowptr,
                          int* __restrict__ cursor, int* __restrict__ elist){
  int e = blockIdx.x*blockDim.x + threadIdx.x;
  if(e<EE){ int d=dst[e]; int p=atomicAdd(&cursor[d],1); elist[rowptr[d]+p]=e; }
}

// ------- time encoding -> relpad [E,112] (cols 100..111 zero) -------
__global__ void k_relenc(const int* __restrict__ src, const int* __restrict__ tt,
                         const int* __restrict__ lu, const float* __restrict__ tw,
                         const float* __restrict__ tb, bf16* __restrict__ rel){
  int i = blockIdx.x*blockDim.x + threadIdx.x;
  if(i >= EE*112) return;
  int e = i/112, c = i - e*112;
  float v = 0.f;
  if(c < 100){
    float rt  = (float)(lu[src[e]] - tt[e]);
    float arg = __fadd_rn(__fmul_rn(rt, tw[c]), tb[c]);
    v = cosf(arg);
  }
  rel[i] = f2b(v);
}

// ------- generic weight transpose: WT[n][k] = W[k][colofs+n], bf16, zero-pad --------
__global__ void k_wt2(const float* __restrict__ W, int K, int N, int colofs, int ncols,
                      bf16* __restrict__ WT, int kpad, int nrows){
  int i = blockIdx.x*blockDim.x + threadIdx.x;
  if(i >= nrows*kpad) return;
  int n = i / kpad, k = i - n*kpad;
  float v = (n<ncols && k<K)? W[(size_t)k*N + colofs + n] : 0.f;
  WT[i] = f2b(v);
}

// ------- conv1 stacked weights: 8 heads x [416 rows: q|k|v|s|pad][128] ---------------
__global__ void k_wtc1(const float* __restrict__ qw, const float* __restrict__ kw,
                       const float* __restrict__ vw, const float* __restrict__ sw,
                       bf16* __restrict__ outp){
  int i = blockIdx.x*blockDim.x + threadIdx.x;
  if(i >= 8*416*128) return;
  int h = i/(416*128), r = (i/128)%416, k = i&127;
  float v = 0.f;
  if(r < 400 && k < 100){
    int s = r/100, n = r - s*100;
    const float* W = s==0? qw : s==1? kw : s==2? vw : sw;
    v = W[(size_t)k*800 + h*100 + n];
  }
  outp[i] = f2b(v);
}

// ------- edge weights [112][256]: k<100 -> rel rows, 128..227 -> msg rows (shifted) ---
__global__ void k_wte(const float* __restrict__ ew, int N, int colofs,
                      bf16* __restrict__ outp){
  int i = blockIdx.x*blockDim.x + threadIdx.x;
  if(i >= 112*256) return;
  int r = i>>8, k = i&255;
  float v = 0.f;
  if(r < 100){
    if(k < 100) v = ew[(size_t)k*N + colofs + r];
    else if(k >= 128 && k < 228) v = ew[(size_t)(k-28)*N + colofs + r];
  }
  outp[i] = f2b(v);
}

// ------- stacked bias ----------------
__global__ void k_bstack(const float* __restrict__ b0, const float* __restrict__ b1,
                         const float* __restrict__ b2, const float* __restrict__ b3,
                         int W, int H, float* __restrict__ outp){
  int i = blockIdx.x*blockDim.x + threadIdx.x;
  if(i >= H*4*W) return;
  int h = i/(4*W), r = i - h*4*W, s = r/W, c = r - s*W;
  const float* b = s==0? b0 : s==1? b1 : s==2? b2 : b3;
  outp[i] = b[h*W + c];
}

// ---------------- direct-fragment MFMA GEMM: no LDS, no barriers ----------------
// Both A and B fragments are 16B global loads in native MFMA layout.
// A row i (optional gather): k<ksplit -> A1 bf16 (rows 16B-aligned, k1valid%8==0),
// else A2 fp32 (k2valid%4==0). WT [>=nstrips*NT*16][kpad] bf16 zero-padded.
// blockIdx.y = n-strip. act: 0 none / 1 relu / 2 tanh.
// MFMA 16x16x32 (m89-verified): A[m=lo][k=quad*8+j], B[k][n=lo], C col=lo,row=quad*4+r.
template<int NT, int MT>
__global__ __launch_bounds__(256) void mm_direct(
    const bf16* __restrict__ A1, int lda1, int ksplit, int k1valid,
    const float* __restrict__ A2, int lda2, int k2valid,
    const int* __restrict__ gather,
    const bf16* __restrict__ WT, int kpad,
    const float* __restrict__ bias,
    bf16* __restrict__ C, int ldc,
    int M, int nvalid, int act)
{
  int tid = threadIdx.x;
  int wave = tid>>6, lane = tid&63;
  int quad = lane>>4, lo = lane&15;
  int nstrip = blockIdx.y;
  WT += (size_t)nstrip*NT*16*kpad;
  if(bias) bias += nstrip*NT*16;
  C  += nstrip*NT*16;
  int nval = nvalid - nstrip*NT*16;
  int base = blockIdx.x*(64*MT) + wave*(16*MT);

  // A row indices (clamped; gather resolved once)
  int arow[MT];
#pragma unroll
  for(int i=0;i<MT;i++){
    int row = base + i*16 + lo;
    int ar = row < M ? row : M-1;
    arow[i] = gather ? gather[ar] : ar;
  }

  f32x4 acc[MT][NT];
#pragma unroll
  for(int i=0;i<MT;i++)
#pragma unroll
    for(int t=0;t<NT;t++) acc[i][t]=(f32x4){0.f,0.f,0.f,0.f};

  for(int k0=0; k0<kpad; k0+=32){
    int k = k0 + quad*8;
    s16x8 af[MT];
#pragma unroll
    for(int i=0;i<MT;i++){
      s16x8 v = (s16x8){0,0,0,0,0,0,0,0};
      if(k < ksplit){
        if(k + 8 <= k1valid)
          v = *(const s16x8*)(A1 + (size_t)arow[i]*lda1 + k);
      } else {
        int kk = k - ksplit;
        const float* ap = A2 + (size_t)arow[i]*lda2 + kk;
        float4 f0 = {0.f,0.f,0.f,0.f}, f1 = {0.f,0.f,0.f,0.f};
        if(kk + 4 <= k2valid) f0 = *(const float4*)ap;
        if(kk + 8 <= k2valid) f1 = *(const float4*)(ap+4);
        v[0]=f2s(f0.x); v[1]=f2s(f0.y); v[2]=f2s(f0.z); v[3]=f2s(f0.w);
        v[4]=f2s(f1.x); v[5]=f2s(f1.y); v[6]=f2s(f1.z); v[7]=f2s(f1.w);
      }
      af[i] = v;
    }
#pragma unroll
    for(int nt=0; nt<NT; nt++){
      s16x8 bfr = *(const s16x8*)(WT + (size_t)(nt*16+lo)*kpad + k);
#pragma unroll
      for(int i=0;i<MT;i++)
        acc[i][nt] = __builtin_amdgcn_mfma_f32_16x16x32_bf16(af[i], bfr, acc[i][nt], 0,0,0);
    }
  }

#pragma unroll
  for(int nt=0; nt<NT; nt++){
    int col = nt*16 + lo;
    if(col >= nval) continue;
    float bv = bias? bias[col] : 0.f;
#pragma unroll
    for(int i=0;i<MT;i++){
      int row0 = base + i*16 + quad*4;
#pragma unroll
      for(int r=0;r<4;r++){
        int row = row0 + r;
        if(row >= M) continue;
        float v = acc[i][nt][r] + bv;
        if(act==1) v = fmaxf(v,0.f);
        else if(act==2) v = tanhf(v);
        C[(size_t)row*ldc+col] = f2b(v);
      }
    }
  }
}

// ------ fused attention: one wave per node; online softmax; skip-add + relu ------
// zpad!=0: also zero output cols 100..111 (for 112-padded h2)
__global__ __launch_bounds__(256) void k_attn(
    const int* __restrict__ rowptr, const int* __restrict__ elist,
    const int* __restrict__ srcv,
    const bf16* __restrict__ qkvs, const bf16* __restrict__ eh,
    bf16* __restrict__ hout, int ldh, int colofs, int zpad)
{
  int wave = threadIdx.x>>6, lane = threadIdx.x&63;
  int node = blockIdx.x*4 + wave;
  if(node >= NN) return;
  bool act = (lane < 50);
  float q0=0.f, q1=0.f;
  const unsigned* qrow = (const unsigned*)(qkvs + (size_t)node*400);
  if(act){ unsigned u = qrow[lane]; q0=u2f_lo(u); q1=u2f_hi(u); }
  int s0 = rowptr[node], s1 = rowptr[node+1];
  float m = -3.4e38f, d = 0.f, a0 = 0.f, a1 = 0.f;
  for(int j=s0; j<s1; j++){
    int e = elist[j];
    int sn = srcv[e];
    float p = 0.f, e0=0.f, e1=0.f;
    if(act){
      unsigned uk = ((const unsigned*)(qkvs + (size_t)sn*400 + 100))[lane];
      unsigned ue = ((const unsigned*)(eh   + (size_t)e*100))[lane];
      e0=u2f_lo(ue); e1=u2f_hi(ue);
      p = q0*(u2f_lo(uk)+e0) + q1*(u2f_hi(uk)+e1);
    }
    for(int off=32; off; off>>=1) p += __shfl_xor(p, off);
    float alpha = p * 0.1f;
    float mn = fmaxf(m, alpha);
    float sc = expf(m - mn);
    float wv = expf(alpha - mn);
    d = d*sc + wv;
    if(act){
      unsigned uv = ((const unsigned*)(qkvs + (size_t)sn*400 + 200))[lane];
      a0 = a0*sc + wv*(u2f_lo(uv)+e0);
      a1 = a1*sc + wv*(u2f_hi(uv)+e1);
    }
    m = mn;
  }
  if(act){
    float inv = 1.f/(d + 1e-16f);
    unsigned us = ((const unsigned*)(qkvs + (size_t)node*400 + 300))[lane];
    float h0 = fmaxf(u2f_lo(us) + a0*inv, 0.f);
    float h1 = fmaxf(u2f_hi(us) + a1*inv, 0.f);
    bf16* op = hout + (size_t)node*ldh + colofs + lane*2;
    op[0] = f2b(h0); op[1] = f2b(h1);
  } else if(zpad && lane < 56){
    bf16* op = hout + (size_t)node*ldh + colofs + lane*2;
    op[0] = f2b(0.f); op[1] = f2b(0.f);
  }
}

// ------ linkpred final layer: out[e] = t3[e] @ w4 + b4 (K=50, N=2, fp32) ------
__global__ void k_lpout(const bf16* __restrict__ t3, const float* __restrict__ w4,
                        const float* __restrict__ b4, float* __restrict__ out,
                        int base, int n){
  int i = blockIdx.x*blockDim.x + threadIdx.x;
  if(i >= n*2) return;
  int g = i>>1, j = i&1;
  const bf16* tp = t3 + (size_t)g*50;
  float s = 0.f;
  for(int k=0;k<50;k++) s += b2f(tp[k])*w4[k*2+j];
  out[(size_t)(base+g)*2 + j] = s + b4[j];
}

extern "C" void kernel_launch(void* const* d_in, const int* in_sizes, int n_in,
                              void* d_out, int out_size, void* d_ws, size_t ws_size,
                              hipStream_t stream){
  const float* x       = (const float*)d_in[0];
  const float* msg     = (const float*)d_in[1];
  const float* time_w  = (const float*)d_in[2];
  const float* time_b  = (const float*)d_in[3];
  const float* c1_qw=(const float*)d_in[4];  const float* c1_qb=(const float*)d_in[5];
  const float* c1_kw=(const float*)d_in[6];  const float* c1_kb=(const float*)d_in[7];
  const float* c1_vw=(const float*)d_in[8];  const float* c1_vb=(const float*)d_in[9];
  const float* c1_ew=(const float*)d_in[10];
  const float* c1_sw=(const float*)d_in[11]; const float* c1_sb=(const float*)d_in[12];
  const float* c2_qw=(const float*)d_in[13]; const float* c2_qb=(const float*)d_in[14];
  const float* c2_kw=(const float*)d_in[15]; const float* c2_kb=(const float*)d_in[16];
  const float* c2_vw=(const float*)d_in[17]; const float* c2_vb=(const float*)d_in[18];
  const float* c2_ew=(const float*)d_in[19];
  const float* c2_sw=(const float*)d_in[20]; const float* c2_sb=(const float*)d_in[21];
  const float* lp_src_w=(const float*)d_in[22]; const float* lp_src_b=(const float*)d_in[23];
  const float* lp_dst_w=(const float*)d_in[24]; const float* lp_dst_b=(const float*)d_in[25];
  const float* lp1_w=(const float*)d_in[26]; const float* lp1_b=(const float*)d_in[27];
  const float* lp2_w=(const float*)d_in[28]; const float* lp2_b=(const float*)d_in[29];
  const float* lp3_w=(const float*)d_in[30]; const float* lp3_b=(const float*)d_in[31];
  const float* lp4_w=(const float*)d_in[32]; const float* lp4_b=(const float*)d_in[33];
  const int* last_update=(const int*)d_in[34];
  const int* tt =(const int*)d_in[35];
  const int* edge_index=(const int*)d_in[36];
  const int* src = edge_index;
  const int* dst = edge_index + EE;
  float* out = (float*)d_out;

  // ---- workspace: peak 199.5 MB (< proved-safe 201.8 MB) ----
  char* ws = (char*)d_ws;
  bf16*  h1    = (bf16*) (ws + 0);             // N*800 bf16
  bf16*  relpad= (bf16*) (ws + 80000000);      // E*112 bf16
  bf16*  eh    = (bf16*) (ws + 113600000);     // E*100 bf16
  bf16*  qkvs  = (bf16*) (ws + 143600000);     // N*400 bf16
  bf16*  h2p   = (bf16*) (ws + 183600000);     // N*112 bf16 (16B-aligned rows)
  int*   rowptr= (int*)  (ws + 194800000);     // N+1
  int*   elist = (int*)  (ws + 195000064);     // E
  int*   deg   = (int*)  (ws + 195600064);     // N
  int*   cursor= (int*)  (ws + 195800064);     // N
  bf16* c1all  = (bf16*)(ws + 196000064);  // 8 x [416][128]
  bf16* c1eall = (bf16*)(ws + 196852032);  // 8 x [112][256]
  bf16* c2all  = (bf16*)(ws + 197310784);  // [416][896]
  bf16* c2e    = (bf16*)(ws + 198056256);  // [112][256]
  bf16* lpswt  = (bf16*)(ws + 198113600);  // [208][128]
  bf16* lpdwt  = (bf16*)(ws + 198166848);  // [208][128]
  bf16* lp1t   = (bf16*)(ws + 198220096);  // [832][512]  (4 n-strips of 208)
  bf16* lp2t   = (bf16*)(ws + 199072064);  // [208][896]
  bf16* lp3t   = (bf16*)(ws + 199444800);  // [64][256]
  float* c1ball= (float*)(ws + 199477568); // [8][400]
  float* c2ball= (float*)(ws + 199490368); // [400] -> ends 199,491,968
  // linkpred-phase overlays (conv buffers 0..183.6MB dead):
  bf16* lhh = (bf16*)(ws + 0);             // EH*400 bf16 = 60 MB
  bf16* lt1 = (bf16*)(ws + 60000000);      // EH*800 bf16 = 120 MB -> 180 MB
  bf16* lt2 = (bf16*)(ws + 0);             // EH*200 bf16 = 30 MB (hh dead)
  bf16* lt3 = (bf16*)(ws + 30000000);      // EH*50  bf16 = 7.5 MB

  // ---- weight conversion ----
  k_wtc1<<<(8*416*128+255)/256,256,0,stream>>>(c1_qw,c1_kw,c1_vw,c1_sw,c1all);
  for(int h=0; h<8; h++)
    k_wte<<<(112*256+255)/256,256,0,stream>>>(c1_ew, 800, h*100, c1eall + (size_t)h*112*256);
  k_wte<<<(112*256+255)/256,256,0,stream>>>(c2_ew, 100, 0, c2e);
  k_wt2<<<(100*896+255)/256,256,0,stream>>>(c2_qw,800,100,0,100,c2all,           896,100);
  k_wt2<<<(100*896+255)/256,256,0,stream>>>(c2_kw,800,100,0,100,c2all+100*896,   896,100);
  k_wt2<<<(100*896+255)/256,256,0,stream>>>(c2_vw,800,100,0,100,c2all+200*896,   896,100);
  k_wt2<<<(116*896+255)/256,256,0,stream>>>(c2_sw,800,100,0,100,c2all+300*896,   896,116);
  k_wt2<<<(208*128+255)/256,256,0,stream>>>(lp_src_w,100,200,0,200,lpswt,128,208);
  k_wt2<<<(208*128+255)/256,256,0,stream>>>(lp_dst_w,100,200,0,200,lpdwt,128,208);
  k_wt2<<<(832*512+255)/256,256,0,stream>>>(lp1_w,400,800,0,800,lp1t,512,832);
  k_wt2<<<(208*896+255)/256,256,0,stream>>>(lp2_w,800,200,0,200,lp2t,896,208);
  k_wt2<<<(64*256+255)/256,256,0,stream>>>(lp3_w,200,50,0,50,lp3t,256,64);
  k_bstack<<<(3200+255)/256,256,0,stream>>>(c1_qb,c1_kb,c1_vb,c1_sb,100,8,c1ball);
  k_bstack<<<(400+255)/256,256,0,stream>>>(c2_qb,c2_kb,c2_vb,c2_sb,100,1,c2ball);

  // ---- CSR build ----
  k_zero   <<<(NN+255)/256, 256, 0, stream>>>(deg, NN);
  k_zero   <<<(NN+255)/256, 256, 0, stream>>>(cursor, NN);
  k_hist   <<<(EE+255)/256, 256, 0, stream>>>(dst, deg);
  k_scan   <<<1, 1024, 0, stream>>>(deg, rowptr);
  k_scatter<<<(EE+255)/256, 256, 0, stream>>>(dst, rowptr, cursor, elist);

  // ---- time encoding ----
  k_relenc<<<(EE*112+255)/256, 256, 0, stream>>>(src, tt, last_update, time_w, time_b, relpad);

  int gN2  = (NN + 127)/128;   // MT=2 blocks cover 128 rows
  int gE2  = (EE + 127)/128;
  int gL2  = (EH + 127)/128;
  int gA   = (NN + 3)/4;

  // ---- conv1: per head = stacked GEMM (2 n-strips) + edge GEMM + fused attention ----
  for(int h=0; h<8; h++){
    mm_direct<13,2><<<dim3(gN2,2),256,0,stream>>>(nullptr,0,0,0, x,100,100, nullptr,
        c1all + (size_t)h*416*128, 128, c1ball + h*400, qkvs,400, NN,400,0);
    mm_direct<7,2><<<gE2,256,0,stream>>>(relpad,112,128,112, msg,100,100, nullptr,
        c1eall + (size_t)h*112*256, 256, nullptr, eh,100, EE,100,0);
    k_attn<<<gA,256,0,stream>>>(rowptr, elist, src, qkvs, eh, h1, 800, h*100, 0);
  }

  // ---- conv2 (h2 written 112-padded, pad cols zeroed) ----
  mm_direct<13,2><<<dim3(gN2,2),256,0,stream>>>(h1,800,896,800, nullptr,0,0, nullptr,
      c2all,896, c2ball, qkvs,400, NN,400,0);
  mm_direct<7,2><<<gE2,256,0,stream>>>(relpad,112,128,112, msg,100,100, nullptr,
      c2e,256, nullptr, eh,100, EE,100,0);
  k_attn<<<gA,256,0,stream>>>(rowptr, elist, src, qkvs, eh, h2p, 112, 0, 1);

  // ---- link predictor: batched direct-MFMA chain, 2 edge-halves ----
  for(int half=0; half<2; half++){
    const int* esrc = src + half*EH;
    const int* edst = dst + half*EH;
    // hh[:,0:200] = h2[src]@Wsrc+b ; hh[:,200:400] = h2[dst]@Wdst+b  (gathered A, K=100)
    mm_direct<13,2><<<gL2,256,0,stream>>>(h2p,112,128,112, nullptr,0,0, esrc,
        lpswt,128, lp_src_b, lhh,400, EH,200,0);
    mm_direct<13,2><<<gL2,256,0,stream>>>(h2p,112,128,112, nullptr,0,0, edst,
        lpdwt,128, lp_dst_b, lhh+200,400, EH,200,0);
    // t1 = tanh(hh@W1+b1): K=400(512), N=800 via 4 n-strips of 208
    mm_direct<13,2><<<dim3(gL2,4),256,0,stream>>>(lhh,400,512,400, nullptr,0,0, nullptr,
        lp1t,512, lp1_b, lt1,800, EH,800,2);
    // t2 = tanh(t1@W2+b2): K=800(896), N=200
    mm_direct<13,2><<<gL2,256,0,stream>>>(lt1,800,896,800, nullptr,0,0, nullptr,
        lp2t,896, lp2_b, lt2,200, EH,200,2);
    // t3 = tanh(t2@W3+b3): K=200(256), N=50
    mm_direct<4,2><<<gL2,256,0,stream>>>(lt2,200,256,200, nullptr,0,0, nullptr,
        lp3t,256, lp3_b, lt3,50, EH,50,2);
    // out = t3@W4+b4
    k_lpout<<<(EH*2+255)/256,256,0,stream>>>(lt3, lp4_w, lp4_b, out, half*EH, EH);
  }

  (void)in_sizes; (void)n_in; (void)out_size; (void)ws_size;
}